// Round 4
// baseline (14792.061 us; speedup 1.0000x reference)
//
#include <hip/hip_runtime.h>

typedef unsigned short u16;
typedef unsigned int u32;
typedef __bf16 bf16x8 __attribute__((ext_vector_type(8)));
typedef float f32x4 __attribute__((ext_vector_type(4)));

#define YD 32
#define ZD 64
#define HD 256
#define RD 256
#define TSTEPS 199   // T-1 scan steps
#define BB 2048
#define MROWS 16     // batch rows per block
#define NBLK 128     // 2048/16
#define NTHR 512     // 8 waves: 0-3=A(recurrence), 4-5=Bp(prior/KL/encH), 6-7=Bd(dec/NLL)
// LDS strides (u16 elements)
#define YS  40
#define ZS  72
#define HS  264
#define HBS 264
#define HES 136
#define HDS 72

#define SB0() __builtin_amdgcn_sched_barrier(0)

// bf16 weight layout offsets inside d_ws (element units, (N,K) row-major, K contiguous)
enum : int {
  OFF_ENC_W1 = 0,        // 256x320
  OFF_ENC_W2 = 81920,    // 256x256
  OFF_ENC_H  = 147456,   // [enc_mw;enc_sw] 128x256
  OFF_PRI_W1 = 180224,   // 256x288
  OFF_PRI_W2 = 253952,   // 256x256
  OFF_PRI_H  = 319488,   // [pri_mw;pri_sw] 128x256
  OFF_DEC_W1 = 352256,   // 256x352
  OFF_DEC_W2 = 442368,   // 256x256
  OFF_DEC_H  = 507904,   // [dec_mw;dec_sw] 64x256
  OFF_GWIH   = 524288,   // 768x96
  OFF_GWHH   = 598016,   // 768x256
};

__device__ __forceinline__ u16 f2bf(float f) {
  u32 u = __float_as_uint(f);
  u += 0x7fffu + ((u >> 16) & 1u);   // RTNE
  return (u16)(u >> 16);
}
__device__ __forceinline__ float bf2f(u16 b) {
  return __uint_as_float((u32)b << 16);
}
__device__ __forceinline__ float softplus_f(float x) {
  float l = __logf(1.f + __expf(-fabsf(x)));
  return x > 0.f ? x + l : l;
}
__device__ __forceinline__ float sigmoid_f(float x) {
  return __builtin_amdgcn_rcpf(1.f + __expf(-x));
}
__device__ __forceinline__ float tanh_f(float x) {
  float e = __expf(-2.f * fabsf(x));
  float t = (1.f - e) * __builtin_amdgcn_rcpf(1.f + e);
  return x >= 0.f ? t : -t;
}

template<int NT, int KS>
struct WF { bf16x8 b[KS][NT]; };

template<int NT, int KS>
__device__ __forceinline__ void wload(WF<NT, KS>& f, const u16* __restrict__ W,
    const int Kw, const int wrow0, const int wk0, const int lane) {
  const int n = lane & 15, quad = lane >> 4;
  #pragma unroll
  for (int nt = 0; nt < NT; ++nt) {
    const u16* wp = W + (size_t)(wrow0 + nt * 16 + n) * Kw + wk0 + quad * 8;
    #pragma unroll
    for (int ks = 0; ks < KS; ++ks)
      f.b[ks][nt] = *reinterpret_cast<const bf16x8*>(wp + ks * 32);
  }
}

// A (LDS, row-major, stride AS): rows 16 batch rows, cols acol0 + ks*32 + quad*8
template<int NT, int KS, int AS>
__device__ __forceinline__ void gemm_b(f32x4 (&acc)[NT][1], const WF<NT, KS>& f,
    const u16* A, const int acol0, const int lane) {
  const int n = lane & 15, quad = lane >> 4;
  #pragma unroll
  for (int ks = 0; ks < KS; ++ks) {
    bf16x8 a = *reinterpret_cast<const bf16x8*>(A + n * AS + acol0 + ks * 32 + quad * 8);
    #pragma unroll
    for (int nt = 0; nt < NT; ++nt)
      acc[nt][0] = __builtin_amdgcn_mfma_f32_16x16x32_bf16(a, f.b[ks][nt], acc[nt][0], 0, 0, 0);
  }
}

template<int NT, int DS>
__device__ __forceinline__ void store_relu_n(const f32x4 (&acc)[NT][1], u16* dst,
    const int col0, const float (&bias)[NT], const int lane)
{
  const int n = lane & 15, quad = lane >> 4;
  #pragma unroll
  for (int nt = 0; nt < NT; ++nt)
    #pragma unroll
    for (int i = 0; i < 4; ++i) {
      float v = fmaxf(acc[nt][0][i] + bias[nt], 0.f);
      dst[(quad * 4 + i) * DS + col0 + nt * 16 + n] = f2bf(v);
    }
}

struct PrepArgs { const float* src[14]; int off[14]; int cnt[14]; };

__global__ void prep_weights(PrepArgs a, u16* __restrict__ dst) {
  const int j = blockIdx.y;
  const float* __restrict__ s = a.src[j];
  u16* d = dst + a.off[j];
  const int nel = a.cnt[j];
  for (int i = blockIdx.x * blockDim.x + threadIdx.x; i < nel; i += gridDim.x * blockDim.x)
    d[i] = f2bf(s[i]);
}

__global__ void zero_out_k(float* out) { if (threadIdx.x < 2) out[threadIdx.x] = 0.f; }

// 4-slot / 3-role schedule, 8 waves, 256-VGPR budget, sched_barrier(0)-fenced
// two-deep load/consume pipeline per slot.
//   A  (w0-3, NT=4): t   : S1 enc1+gh_r | S2 enc2+gh_u | S3 gh_n      | S4 gi+gates+h
//   Bp (w4-5, NT=8): t-1 : S1 pri1      | S2 pri2      | S3 encH+z(t)+priH | S4 KL+y-stage
//   Bd (w6-7, NT=8): t-1 : S1 dec1      | S2 dec2      | S3 decH      | S4 NLL
__global__ __launch_bounds__(NTHR, 2)
void vrnn_kernel(const float* __restrict__ states, const float* __restrict__ eps,
                 const float* __restrict__ enc_b1, const float* __restrict__ enc_b2,
                 const float* __restrict__ enc_mb, const float* __restrict__ enc_sb,
                 const float* __restrict__ pri_b1, const float* __restrict__ pri_b2,
                 const float* __restrict__ pri_mb, const float* __restrict__ pri_sb,
                 const float* __restrict__ dec_b1, const float* __restrict__ dec_b2,
                 const float* __restrict__ dec_mb, const float* __restrict__ dec_sb,
                 const float* __restrict__ gbih, const float* __restrict__ gbhh,
                 const u16* __restrict__ ws, float* __restrict__ out)
{
  __shared__ __align__(16) u16 yb[3][MROWS * YS];
  __shared__ __align__(16) u16 zb[2][MROWS * ZS];
  __shared__ __align__(16) u16 hbuf[2][MROWS * HS];
  __shared__ __align__(16) u16 hb1A[MROWS * HBS], hb2A[MROWS * HBS];
  __shared__ __align__(16) u16 hb1P[MROWS * HBS], hb2P[MROWS * HBS];
  __shared__ __align__(16) u16 hb1D[MROWS * HBS], hb2D[MROWS * HBS];
  __shared__ __align__(16) u16 hbhE[2][MROWS * HES];
  __shared__ __align__(16) u16 hbhP[MROWS * HES];
  __shared__ __align__(16) u16 hbhD[MROWS * HDS];

  const int tid = threadIdx.x;
  const int w = tid >> 6, lane = tid & 63;
  const int n = lane & 15, quad = lane >> 4;
  const int r0 = blockIdx.x * MROWS;
  const int n0A = w * 64;          // A-wave 64-col strip (w<4)
  const int n0B = (w & 1) * 128;   // Bp/Bd 128-col strip

  const u16* __restrict__ wE1 = ws + OFF_ENC_W1;
  const u16* __restrict__ wE2 = ws + OFF_ENC_W2;
  const u16* __restrict__ wEH = ws + OFF_ENC_H;
  const u16* __restrict__ wP1 = ws + OFF_PRI_W1;
  const u16* __restrict__ wP2 = ws + OFF_PRI_W2;
  const u16* __restrict__ wPH = ws + OFF_PRI_H;
  const u16* __restrict__ wD1 = ws + OFF_DEC_W1;
  const u16* __restrict__ wD2 = ws + OFF_DEC_W2;
  const u16* __restrict__ wDH = ws + OFF_DEC_H;
  const u16* __restrict__ wGI = ws + OFF_GWIH;
  const u16* __restrict__ wGH = ws + OFF_GWHH;

  // ---- role-specific hoisted bias scalars ----
  float b1e[4] = {}, b2e[4] = {}, brg[4] = {}, bug[4] = {}, bing[4] = {}, bhng[4] = {};
  float b1p[8] = {}, b2p[8] = {}, mbE2[2] = {}, sbE2[2] = {}, bhPm[2] = {}, bhPs[2] = {};
  float b1d[8] = {}, b2d[8] = {}, bhDm = 0.f, bhDs = 0.f;
  if (w < 4) {
    #pragma unroll
    for (int s = 0; s < 4; ++s) {
      const int c = n0A + s * 16 + n;
      b1e[s] = enc_b1[c]; b2e[s] = enc_b2[c];
      brg[s] = gbih[c] + gbhh[c];
      bug[s] = gbih[RD + c] + gbhh[RD + c];
      bing[s] = gbih[2 * RD + c];
      bhng[s] = gbhh[2 * RD + c];
    }
  } else if (w < 6) {
    const int p = w - 4;
    #pragma unroll
    for (int k = 0; k < 8; ++k) {
      const int c = n0B + k * 16 + n;
      b1p[k] = pri_b1[c]; b2p[k] = pri_b2[c];
    }
    #pragma unroll
    for (int s = 0; s < 2; ++s) {
      const int d = p * 32 + s * 16 + n;
      mbE2[s] = enc_mb[d]; sbE2[s] = enc_sb[d];
      bhPm[s] = pri_mb[d]; bhPs[s] = pri_sb[d];
    }
  } else {
    const int q = w - 6;
    #pragma unroll
    for (int k = 0; k < 8; ++k) {
      const int c = n0B + k * 16 + n;
      b1d[k] = dec_b1[c]; b2d[k] = dec_b2[c];
    }
    bhDm = dec_mb[q * 16 + n]; bhDs = dec_sb[q * 16 + n];
  }

  // ---- prologue: zero h_0, stage y_0 -> yb[0], y_1 -> yb[1] ----
  for (int i = tid; i < MROWS * (HD / 2); i += NTHR) {
    int row = i >> 7, c = (i & 127) * 2;
    *reinterpret_cast<u32*>(&hbuf[0][row * HS + c]) = 0u;
  }
  if (tid < 256) {
    const int row = tid >> 4, c2 = (tid & 15) * 2;
    float2 a0 = *reinterpret_cast<const float2*>(states + ((size_t)0 * BB + r0 + row) * YD + c2);
    float2 a1 = *reinterpret_cast<const float2*>(states + ((size_t)1 * BB + r0 + row) * YD + c2);
    yb[0][row * YS + c2] = f2bf(a0.x); yb[0][row * YS + c2 + 1] = f2bf(a0.y);
    yb[1][row * YS + c2] = f2bf(a1.x); yb[1][row * YS + c2 + 1] = f2bf(a1.y);
  }
  __syncthreads();

  float hreg[4][4];  // A-wave fp32 master h (cols n0A+s*16+n, rows quad*4+i)
  #pragma unroll
  for (int s = 0; s < 4; ++s)
    #pragma unroll
    for (int i = 0; i < 4; ++i) hreg[s][i] = 0.f;

  float kl_acc = 0.f, nll_acc = 0.f;
  int ym0 = 0, ym1 = 1, ym2 = 2;

  for (int t = 0; t <= TSTEPS; ++t) {
    const int pa = t & 1, pb = pa ^ 1;
    f32x4 agh[3][4][1] = {};  // A: gh accumulators (r,u,n), persist S1->S4

    // ================ S1 ================
    if (w < 4) {
      if (t < TSTEPS) {
        WF<4,1> fx, fy; WF<4,4> fh0, fh1, fg0, fg1;
        wload(fx, wE1, 320, n0A, 0, lane);
        wload(fy, wE1, 320, n0A, 32, lane); SB0();
        wload(fh0, wE1, 320, n0A, 64, lane); SB0();
        f32x4 acc[4][1] = {};
        gemm_b<4,1,YS>(acc, fx, yb[ym1], 0, lane);
        gemm_b<4,1,YS>(acc, fy, yb[ym0], 0, lane); SB0();
        wload(fh1, wE1, 320, n0A, 192, lane); SB0();
        gemm_b<4,4,HS>(acc, fh0, hbuf[pa], 0, lane); SB0();
        wload(fg0, wGH, 256, n0A, 0, lane); SB0();
        gemm_b<4,4,HS>(acc, fh1, hbuf[pa], 128, lane); SB0();
        wload(fg1, wGH, 256, n0A, 128, lane); SB0();
        store_relu_n<4, HBS>(acc, hb1A, n0A, b1e, lane);
        gemm_b<4,4,HS>(agh[0], fg0, hbuf[pa], 0, lane); SB0();
        gemm_b<4,4,HS>(agh[0], fg1, hbuf[pa], 128, lane);
      }
    } else if (w < 6) {
      if (t > 0) {
        WF<8,1> py; WF<8,2> ph0, ph1, ph2, ph3;
        wload(py, wP1, 288, n0B, 0, lane);
        wload(ph0, wP1, 288, n0B, 32, lane); SB0();
        wload(ph1, wP1, 288, n0B, 96, lane); SB0();
        f32x4 acc[8][1] = {};
        gemm_b<8,1,YS>(acc, py, yb[ym2], 0, lane);
        gemm_b<8,2,HS>(acc, ph0, hbuf[pb], 0, lane); SB0();
        wload(ph2, wP1, 288, n0B, 160, lane); SB0();
        gemm_b<8,2,HS>(acc, ph1, hbuf[pb], 64, lane); SB0();
        wload(ph3, wP1, 288, n0B, 224, lane); SB0();
        gemm_b<8,2,HS>(acc, ph2, hbuf[pb], 128, lane);
        gemm_b<8,2,HS>(acc, ph3, hbuf[pb], 192, lane);
        store_relu_n<8, HBS>(acc, hb1P, n0B, b1p, lane);
      }
    } else {
      if (t > 0) {
        WF<8,1> dy; WF<8,2> dz, dh0, dh1, dh2, dh3;
        wload(dy, wD1, 352, n0B, 0, lane);
        wload(dz, wD1, 352, n0B, 32, lane); SB0();
        wload(dh0, wD1, 352, n0B, 96, lane); SB0();
        f32x4 acc[8][1] = {};
        gemm_b<8,1,YS>(acc, dy, yb[ym2], 0, lane);
        gemm_b<8,2,ZS>(acc, dz, zb[pb], 0, lane); SB0();
        wload(dh1, wD1, 352, n0B, 160, lane); SB0();
        gemm_b<8,2,HS>(acc, dh0, hbuf[pb], 0, lane); SB0();
        wload(dh2, wD1, 352, n0B, 224, lane); SB0();
        gemm_b<8,2,HS>(acc, dh1, hbuf[pb], 64, lane); SB0();
        wload(dh3, wD1, 352, n0B, 288, lane); SB0();
        gemm_b<8,2,HS>(acc, dh2, hbuf[pb], 128, lane);
        gemm_b<8,2,HS>(acc, dh3, hbuf[pb], 192, lane);
        store_relu_n<8, HBS>(acc, hb1D, n0B, b1d, lane);
      }
    }
    __syncthreads();

    // ================ S2 ================
    if (w < 4) {
      if (t < TSTEPS) {
        WF<4,4> e2a, e2b, g1a, g1b;
        wload(e2a, wE2, 256, n0A, 0, lane); SB0();
        wload(e2b, wE2, 256, n0A, 128, lane); SB0();
        f32x4 acc[4][1] = {};
        gemm_b<4,4,HBS>(acc, e2a, hb1A, 0, lane); SB0();
        wload(g1a, wGH, 256, RD + n0A, 0, lane); SB0();
        gemm_b<4,4,HBS>(acc, e2b, hb1A, 128, lane); SB0();
        wload(g1b, wGH, 256, RD + n0A, 128, lane); SB0();
        store_relu_n<4, HBS>(acc, hb2A, n0A, b2e, lane);
        gemm_b<4,4,HS>(agh[1], g1a, hbuf[pa], 0, lane); SB0();
        gemm_b<4,4,HS>(agh[1], g1b, hbuf[pa], 128, lane);
      }
    } else if (w < 6) {
      if (t > 0) {
        WF<8,2> q0, q1, q2, q3;
        wload(q0, wP2, 256, n0B, 0, lane); SB0();
        wload(q1, wP2, 256, n0B, 64, lane); SB0();
        f32x4 acc[8][1] = {};
        gemm_b<8,2,HBS>(acc, q0, hb1P, 0, lane); SB0();
        wload(q2, wP2, 256, n0B, 128, lane); SB0();
        gemm_b<8,2,HBS>(acc, q1, hb1P, 64, lane); SB0();
        wload(q3, wP2, 256, n0B, 192, lane); SB0();
        gemm_b<8,2,HBS>(acc, q2, hb1P, 128, lane);
        gemm_b<8,2,HBS>(acc, q3, hb1P, 192, lane);
        store_relu_n<8, HBS>(acc, hb2P, n0B, b2p, lane);
      }
    } else {
      if (t > 0) {
        WF<8,2> q0, q1, q2, q3;
        wload(q0, wD2, 256, n0B, 0, lane); SB0();
        wload(q1, wD2, 256, n0B, 64, lane); SB0();
        f32x4 acc[8][1] = {};
        gemm_b<8,2,HBS>(acc, q0, hb1D, 0, lane); SB0();
        wload(q2, wD2, 256, n0B, 128, lane); SB0();
        gemm_b<8,2,HBS>(acc, q1, hb1D, 64, lane); SB0();
        wload(q3, wD2, 256, n0B, 192, lane); SB0();
        gemm_b<8,2,HBS>(acc, q2, hb1D, 128, lane);
        gemm_b<8,2,HBS>(acc, q3, hb1D, 192, lane);
        store_relu_n<8, HBS>(acc, hb2D, n0B, b2d, lane);
      }
    }
    __syncthreads();

    // ================ S3 ================
    if (w < 4) {
      if (t < TSTEPS) {
        WF<4,4> g2a, g2b;
        wload(g2a, wGH, 256, 2 * RD + n0A, 0, lane); SB0();
        wload(g2b, wGH, 256, 2 * RD + n0A, 128, lane); SB0();
        gemm_b<4,4,HS>(agh[2], g2a, hbuf[pa], 0, lane); SB0();
        gemm_b<4,4,HS>(agh[2], g2b, hbuf[pa], 128, lane);
      }
    } else if (w < 6) {
      const int p = w - 4;
      if (t < TSTEPS) {   // encH for step t + z-sample
        float ev[2][4];
        #pragma unroll
        for (int s = 0; s < 2; ++s)
          #pragma unroll
          for (int i = 0; i < 4; ++i)
            ev[s][i] = eps[((size_t)t * BB + r0 + quad * 4 + i) * ZD + p * 32 + s * 16 + n];
        WF<2,4> ema, emb, esa, esb;
        wload(ema, wEH, 256, p * 32, 0, lane);
        wload(emb, wEH, 256, p * 32, 128, lane); SB0();
        wload(esa, wEH, 256, 64 + p * 32, 0, lane);
        wload(esb, wEH, 256, 64 + p * 32, 128, lane); SB0();
        f32x4 aem[2][1] = {}, aes[2][1] = {};
        gemm_b<2,4,HBS>(aem, ema, hb2A, 0, lane);
        gemm_b<2,4,HBS>(aem, emb, hb2A, 128, lane);
        gemm_b<2,4,HBS>(aes, esa, hb2A, 0, lane);
        gemm_b<2,4,HBS>(aes, esb, hb2A, 128, lane);
        u16* he = hbhE[pa];
        #pragma unroll
        for (int s = 0; s < 2; ++s)
          #pragma unroll
          for (int i = 0; i < 4; ++i) {
            const int row = quad * 4 + i, d = p * 32 + s * 16 + n;
            u16 bm = f2bf(aem[s][0][i] + mbE2[s]);
            u16 bs = f2bf(softplus_f(aes[s][0][i] + sbE2[s]));
            he[row * HES + d] = bm;
            he[row * HES + 64 + d] = bs;
            zb[pa][row * ZS + d] = f2bf(bf2f(bm) + bf2f(bs) * ev[s][i]);
          }
      }
      if (t > 0) {        // priH for step t-1
        WF<2,4> pma, pmb, psa, psb;
        wload(pma, wPH, 256, p * 32, 0, lane);
        wload(pmb, wPH, 256, p * 32, 128, lane); SB0();
        wload(psa, wPH, 256, 64 + p * 32, 0, lane);
        wload(psb, wPH, 256, 64 + p * 32, 128, lane); SB0();
        f32x4 apm[2][1] = {}, aps[2][1] = {};
        gemm_b<2,4,HBS>(apm, pma, hb2P, 0, lane);
        gemm_b<2,4,HBS>(apm, pmb, hb2P, 128, lane);
        gemm_b<2,4,HBS>(aps, psa, hb2P, 0, lane);
        gemm_b<2,4,HBS>(aps, psb, hb2P, 128, lane);
        #pragma unroll
        for (int s = 0; s < 2; ++s)
          #pragma unroll
          for (int i = 0; i < 4; ++i) {
            const int row = quad * 4 + i, d = p * 32 + s * 16 + n;
            hbhP[row * HES + d] = f2bf(apm[s][0][i] + bhPm[s]);
            hbhP[row * HES + 64 + d] = f2bf(softplus_f(aps[s][0][i] + bhPs[s]));
          }
      }
    } else {
      if (t > 0) {        // decH for step t-1
        const int q = w - 6;
        WF<1,4> m0, m1, s0, s1;
        wload(m0, wDH, 256, q * 16, 0, lane);
        wload(m1, wDH, 256, q * 16, 128, lane); SB0();
        wload(s0, wDH, 256, 32 + q * 16, 0, lane);
        wload(s1, wDH, 256, 32 + q * 16, 128, lane); SB0();
        f32x4 adm[1][1] = {}, ads[1][1] = {};
        gemm_b<1,4,HBS>(adm, m0, hb2D, 0, lane);
        gemm_b<1,4,HBS>(adm, m1, hb2D, 128, lane);
        gemm_b<1,4,HBS>(ads, s0, hb2D, 0, lane);
        gemm_b<1,4,HBS>(ads, s1, hb2D, 128, lane);
        #pragma unroll
        for (int i = 0; i < 4; ++i) {
          const int row = quad * 4 + i;
          hbhD[row * HDS + q * 16 + n] = f2bf(adm[0][0][i] + bhDm);
          hbhD[row * HDS + 32 + q * 16 + n] = f2bf(softplus_f(ads[0][0][i] + bhDs));
        }
      }
    }
    __syncthreads();

    // ================ S4 ================
    if (w < 4) {
      if (t < TSTEPS) {
        WF<4,1> rx, ux, nx; WF<4,2> rz, uz, nz;
        wload(rx, wGI, 96, n0A, 0, lane);
        wload(rz, wGI, 96, n0A, 32, lane); SB0();
        wload(ux, wGI, 96, RD + n0A, 0, lane);
        wload(uz, wGI, 96, RD + n0A, 32, lane); SB0();
        {
          f32x4 agi[4][1] = {};
          gemm_b<4,1,YS>(agi, rx, yb[ym1], 0, lane);
          gemm_b<4,2,ZS>(agi, rz, zb[pa], 0, lane);
          #pragma unroll
          for (int s = 0; s < 4; ++s)
            #pragma unroll
            for (int i = 0; i < 4; ++i) {
              float r = sigmoid_f(agi[s][0][i] + agh[0][s][0][i] + brg[s]);
              agh[2][s][0][i] = r * (agh[2][s][0][i] + bhng[s]);
            }
        }
        SB0();
        wload(nx, wGI, 96, 2 * RD + n0A, 0, lane);
        wload(nz, wGI, 96, 2 * RD + n0A, 32, lane); SB0();
        {
          f32x4 agi[4][1] = {};
          gemm_b<4,1,YS>(agi, ux, yb[ym1], 0, lane);
          gemm_b<4,2,ZS>(agi, uz, zb[pa], 0, lane);
          #pragma unroll
          for (int s = 0; s < 4; ++s)
            #pragma unroll
            for (int i = 0; i < 4; ++i)
              agh[1][s][0][i] = sigmoid_f(agi[s][0][i] + agh[1][s][0][i] + bug[s]);
        }
        SB0();
        {
          f32x4 agi[4][1] = {};
          gemm_b<4,1,YS>(agi, nx, yb[ym1], 0, lane);
          gemm_b<4,2,ZS>(agi, nz, zb[pa], 0, lane);
          u16* hn = hbuf[pb];
          #pragma unroll
          for (int s = 0; s < 4; ++s)
            #pragma unroll
            for (int i = 0; i < 4; ++i) {
              float nn = tanh_f(agi[s][0][i] + bing[s] + agh[2][s][0][i]);
              float u = agh[1][s][0][i];
              float hv = (1.f - u) * nn + u * hreg[s][i];
              hreg[s][i] = hv;
              hn[(quad * 4 + i) * HS + n0A + s * 16 + n] = f2bf(hv);
            }
        }
      }
    } else if (w < 6) {
      const int e = (w - 4) * 64 + lane;  // 0..127
      if (t + 2 <= TSTEPS) {              // stage y_{t+2}
        const int row = e >> 3, c4 = (e & 7) * 4;
        float4 v = *reinterpret_cast<const float4*>(states + ((size_t)(t + 2) * BB + r0 + row) * YD + c4);
        u16* dd = &yb[ym2][row * YS + c4];
        dd[0] = f2bf(v.x); dd[1] = f2bf(v.y); dd[2] = f2bf(v.z); dd[3] = f2bf(v.w);
      }
      if (t > 0) {                        // KL for step t-1
        const u16* he = hbhE[pb];
        const int m = e >> 3, j0 = (e & 7) * 8;
        #pragma unroll
        for (int k = 0; k < 8; ++k) {
          const int j = j0 + k;
          float em = bf2f(he[m * HES + j]);
          float es = bf2f(he[m * HES + 64 + j]);
          float pm = bf2f(hbhP[m * HES + j]);
          float ps = bf2f(hbhP[m * HES + 64 + j]);
          float d = em - pm;
          kl_acc += 0.5f * (2.f * __logf(ps * __builtin_amdgcn_rcpf(es))
                            + (es * es + d * d) / (ps * ps) - 1.f);
        }
      }
    } else {
      if (t > 0) {                        // NLL for step t-1
        const int e = (w - 6) * 64 + lane, m = e >> 3, j = (e & 7) * 4;
        float4 xv = *reinterpret_cast<const float4*>(states + ((size_t)t * BB + r0 + m) * YD + j);
        #pragma unroll
        for (int c = 0; c < 4; ++c) {
          float dm = bf2f(hbhD[m * HDS + j + c]);
          float ds = bf2f(hbhD[m * HDS + 32 + j + c]);
          float xf = (c == 0) ? xv.x : (c == 1) ? xv.y : (c == 2) ? xv.z : xv.w;
          float dd = xf - dm;
          nll_acc += __logf(ds) + dd * dd / (2.f * ds * ds) + 0.91893853320467274178f;
        }
      }
    }
    __syncthreads();

    const int tmp = ym0; ym0 = ym1; ym1 = ym2; ym2 = tmp;
  }

  // ---- final reduction ----
  float kv = kl_acc, nv = nll_acc;
  #pragma unroll
  for (int off = 32; off > 0; off >>= 1) {
    kv += __shfl_down(kv, off, 64);
    nv += __shfl_down(nv, off, 64);
  }
  if (lane == 0) {
    atomicAdd(out + 0, kv);
    atomicAdd(out + 1, nv);
  }
}

extern "C" void kernel_launch(void* const* d_in, const int* in_sizes, int n_in,
                              void* d_out, int out_size, void* d_ws, size_t ws_size,
                              hipStream_t stream) {
  const float* states = (const float*)d_in[0];
  const float* eps    = (const float*)d_in[1];
  u16* ws   = (u16*)d_ws;
  float* out = (float*)d_out;

  PrepArgs pa;
  const int jsrc[14] = {2, 4, 6, 8, 10, 12, 14, 16, 18, 20, 22, 24, 26, 27};
  const int joff[14] = {OFF_ENC_W1, OFF_ENC_W2, OFF_ENC_H, OFF_ENC_H + 16384,
                        OFF_PRI_W1, OFF_PRI_W2, OFF_PRI_H, OFF_PRI_H + 16384,
                        OFF_DEC_W1, OFF_DEC_W2, OFF_DEC_H, OFF_DEC_H + 8192,
                        OFF_GWIH, OFF_GWHH};
  const int jcnt[14] = {81920, 65536, 16384, 16384,
                        73728, 65536, 16384, 16384,
                        90112, 65536, 8192, 8192,
                        73728, 196608};
  for (int j = 0; j < 14; ++j) {
    pa.src[j] = (const float*)d_in[jsrc[j]];
    pa.off[j] = joff[j];
    pa.cnt[j] = jcnt[j];
  }

  zero_out_k<<<dim3(1), dim3(64), 0, stream>>>(out);
  prep_weights<<<dim3(64, 14), dim3(256), 0, stream>>>(pa, ws);
  vrnn_kernel<<<dim3(NBLK), dim3(NTHR), 0, stream>>>(
      states, eps,
      (const float*)d_in[3],  (const float*)d_in[5],
      (const float*)d_in[7],  (const float*)d_in[9],
      (const float*)d_in[11], (const float*)d_in[13],
      (const float*)d_in[15], (const float*)d_in[17],
      (const float*)d_in[19], (const float*)d_in[21],
      (const float*)d_in[23], (const float*)d_in[25],
      (const float*)d_in[28], (const float*)d_in[29],
      ws, out);
}

// Round 6
// 10030.526 us; speedup vs baseline: 1.4747x; 1.4747x over previous
//
#include <hip/hip_runtime.h>

typedef unsigned short u16;
typedef unsigned int u32;
typedef __bf16 bf16x8 __attribute__((ext_vector_type(8)));
typedef float f32x4 __attribute__((ext_vector_type(4)));
typedef float f32x2 __attribute__((ext_vector_type(2)));

#define YD 32
#define ZD 64
#define HD 256
#define RD 256
#define TSTEPS 199   // T-1 scan steps
#define BB 2048
#define MROWS 16     // batch rows per block
#define NBLK 128     // 2048/16
#define NTHR 1024    // 16 waves: 0-7=A(recurrence), 8-11=Bp(prior/KL), 12-15=Bd(dec/NLL)
// LDS strides (u16 elements); all *2B are multiples of 16B, pads break pow2 banks
#define YS  40       // y rows (32 + 8 pad)
#define ZS  72       // z rows (64 + 8)
#define HS  264      // h rows (256 + 8)
#define HBS 264      // hidden-layer bufs
#define HES 136      // enc/pri head bufs [m|s](128) + 8
#define HDS 72       // dec head buf [dm|ds](64) + 8

// bf16 weight layout offsets inside d_ws (element units, (N,K) row-major, K contiguous)
enum : int {
  OFF_ENC_W1 = 0,        // 256x320
  OFF_ENC_W2 = 81920,    // 256x256
  OFF_ENC_H  = 147456,   // [enc_mw;enc_sw] 128x256
  OFF_PRI_W1 = 180224,   // 256x288
  OFF_PRI_W2 = 253952,   // 256x256
  OFF_PRI_H  = 319488,   // [pri_mw;pri_sw] 128x256
  OFF_DEC_W1 = 352256,   // 256x352
  OFF_DEC_W2 = 442368,   // 256x256
  OFF_DEC_H  = 507904,   // [dec_mw;dec_sw] 64x256
  OFF_GWIH   = 524288,   // 768x96
  OFF_GWHH   = 598016,   // 768x256
};

__device__ __forceinline__ u16 f2bf(float f) {
  u32 u = __float_as_uint(f);
  u += 0x7fffu + ((u >> 16) & 1u);   // RTNE
  return (u16)(u >> 16);
}
__device__ __forceinline__ float bf2f(u16 b) {
  return __uint_as_float((u32)b << 16);
}
__device__ __forceinline__ float softplus_f(float x) {
  float l = __logf(1.f + __expf(-fabsf(x)));
  return x > 0.f ? x + l : l;
}
__device__ __forceinline__ float sigmoid_f(float x) {
  return __builtin_amdgcn_rcpf(1.f + __expf(-x));
}
__device__ __forceinline__ float tanh_f(float x) {
  float e = __expf(-2.f * fabsf(x));
  float t = (1.f - e) * __builtin_amdgcn_rcpf(1.f + e);
  return x >= 0.f ? t : -t;
}
// Non-temporal stream loads: states/eps are read-once streams; nt keeps them
// from allocating in L2/L3 so the 1.55 MB weight set stays cache-resident.
// (ext_vector_type, not HIP float2 — the builtin rejects class types.)
__device__ __forceinline__ f32x2 nt_ld2(const float* p) {
  return __builtin_nontemporal_load(reinterpret_cast<const f32x2*>(p));
}
__device__ __forceinline__ float nt_ld(const float* p) {
  return __builtin_nontemporal_load(p);
}

// Wave-level GEMM over one contiguous K-segment, batched B loads first.
// A (LDS, row-major, stride AS): rows (rt0+rt)*16+(lane&15), cols acol0+ks*32+quad*8
// W (global bf16, (N,Kw) row-major): rows wrow0+nt*16+(lane&15), cols wk0+ks*32+quad*8
// D[nt][rt] += sum_k A[m][k]*W[n][k]  (act @ W.T)
template<int NT, int RT, int KS, int AS>
__device__ __forceinline__ void gemm_seg(f32x4 (&acc)[NT][RT],
    const u16* __restrict__ W, const int Kw, const int wrow0, const int wk0,
    const u16* A, const int acol0, const int rt0, const int lane)
{
  const int n = lane & 15, quad = lane >> 4;
  bf16x8 b[KS][NT];
  #pragma unroll
  for (int nt = 0; nt < NT; ++nt) {
    const u16* wp = W + (size_t)(wrow0 + nt * 16 + n) * Kw + wk0 + quad * 8;
    #pragma unroll
    for (int ks = 0; ks < KS; ++ks)
      b[ks][nt] = *reinterpret_cast<const bf16x8*>(wp + ks * 32);
  }
  #pragma unroll
  for (int ks = 0; ks < KS; ++ks) {
    bf16x8 a[RT];
    #pragma unroll
    for (int rt = 0; rt < RT; ++rt)
      a[rt] = *reinterpret_cast<const bf16x8*>(A + ((rt0 + rt) * 16 + n) * AS + acol0 + ks * 32 + quad * 8);
    #pragma unroll
    for (int nt = 0; nt < NT; ++nt)
      #pragma unroll
      for (int rt = 0; rt < RT; ++rt)
        acc[nt][rt] = __builtin_amdgcn_mfma_f32_16x16x32_bf16(a[rt], b[ks][nt], acc[nt][rt], 0, 0, 0);
  }
}

// bias + ReLU + bf16 store (RT=1, NT strips of 16 cols)
template<int NT, int DS>
__device__ __forceinline__ void store_relu_n(const f32x4 (&acc)[NT][1], u16* dst,
    const int col0, const float (&bias)[NT], const int lane)
{
  const int n = lane & 15, quad = lane >> 4;
  #pragma unroll
  for (int nt = 0; nt < NT; ++nt)
    #pragma unroll
    for (int i = 0; i < 4; ++i) {
      float v = fmaxf(acc[nt][0][i] + bias[nt], 0.f);
      dst[(quad * 4 + i) * DS + col0 + nt * 16 + n] = f2bf(v);
    }
}

struct PrepArgs { const float* src[14]; int off[14]; int cnt[14]; };

__global__ void prep_weights(PrepArgs a, u16* __restrict__ dst) {
  const int j = blockIdx.y;
  const float* __restrict__ s = a.src[j];
  u16* d = dst + a.off[j];
  const int nel = a.cnt[j];
  for (int i = blockIdx.x * blockDim.x + threadIdx.x; i < nel; i += gridDim.x * blockDim.x)
    d[i] = f2bf(s[i]);
}

__global__ void zero_out_k(float* out) { if (threadIdx.x < 2) out[threadIdx.x] = 0.f; }

// 4-slot / 3-role pipelined schedule (R1 structure; only states/eps loads
// are now non-temporal to stop L2/L3 eviction of the weight set):
//   A  (waves 0-7):  step t   : S1 enc1+gh_r | S2 enc2+gh_un | S3 encH+z | S4 gi+gates+h_new
//   Bp (waves 8-11): step t-1 : S1 pri1      | S2 pri2       | S3 priH   | S4 KL + stage y_{t+2}
//   Bd (waves 12-15):step t-1 : S1 dec1      | S2 dec2       | S3 decH   | S4 NLL
// Buffers: h double (parity t&1 holds h_t), z double, hbhE double, y triple (t%3).
__global__ __launch_bounds__(NTHR, 4)
void vrnn_kernel(const float* __restrict__ states, const float* __restrict__ eps,
                 const float* __restrict__ enc_b1, const float* __restrict__ enc_b2,
                 const float* __restrict__ enc_mb, const float* __restrict__ enc_sb,
                 const float* __restrict__ pri_b1, const float* __restrict__ pri_b2,
                 const float* __restrict__ pri_mb, const float* __restrict__ pri_sb,
                 const float* __restrict__ dec_b1, const float* __restrict__ dec_b2,
                 const float* __restrict__ dec_mb, const float* __restrict__ dec_sb,
                 const float* __restrict__ gbih, const float* __restrict__ gbhh,
                 const u16* __restrict__ ws, float* __restrict__ out)
{
  __shared__ __align__(16) u16 yb[3][MROWS * YS];     // y_t triple buffer (t%3)
  __shared__ __align__(16) u16 zb[2][MROWS * ZS];     // z_t double buffer (t&1)
  __shared__ __align__(16) u16 hbuf[2][MROWS * HS];   // h_t double buffer (t&1)
  __shared__ __align__(16) u16 hb1A[MROWS * HBS], hb2A[MROWS * HBS];
  __shared__ __align__(16) u16 hb1P[MROWS * HBS], hb2P[MROWS * HBS];
  __shared__ __align__(16) u16 hb1D[MROWS * HBS], hb2D[MROWS * HBS];
  __shared__ __align__(16) u16 hbhE[2][MROWS * HES];  // enc heads double buffer (t&1)
  __shared__ __align__(16) u16 hbhP[MROWS * HES];
  __shared__ __align__(16) u16 hbhD[MROWS * HDS];

  const int tid = threadIdx.x;
  const int w = tid >> 6, lane = tid & 63;
  const int n = lane & 15, quad = lane >> 4;
  const int r0 = blockIdx.x * MROWS;
  const int n0A = w * 32;   // A-wave 32-col strip base (valid for w<8)

  const u16* __restrict__ wE1 = ws + OFF_ENC_W1;
  const u16* __restrict__ wE2 = ws + OFF_ENC_W2;
  const u16* __restrict__ wEH = ws + OFF_ENC_H;
  const u16* __restrict__ wP1 = ws + OFF_PRI_W1;
  const u16* __restrict__ wP2 = ws + OFF_PRI_W2;
  const u16* __restrict__ wPH = ws + OFF_PRI_H;
  const u16* __restrict__ wD1 = ws + OFF_DEC_W1;
  const u16* __restrict__ wD2 = ws + OFF_DEC_W2;
  const u16* __restrict__ wDH = ws + OFF_DEC_H;
  const u16* __restrict__ wGI = ws + OFF_GWIH;
  const u16* __restrict__ wGH = ws + OFF_GWHH;

  // ---- role-specific hoisted bias scalars ----
  float b1e[2] = {}, b2e[2] = {}, brg[2] = {}, bug[2] = {}, bing[2] = {}, bhng[2] = {};
  float mbE = 0.f, sbE = 0.f;
  float b1p[4] = {}, b2p[4] = {}, bhP[2] = {};
  float b1d[4] = {}, b2d[4] = {}, bhD = 0.f;
  if (w < 8) {
    #pragma unroll
    for (int s = 0; s < 2; ++s) {
      const int c = n0A + s * 16 + n;
      b1e[s] = enc_b1[c]; b2e[s] = enc_b2[c];
      brg[s] = gbih[c] + gbhh[c];
      bug[s] = gbih[RD + c] + gbhh[RD + c];
      bing[s] = gbih[2 * RD + c];
      bhng[s] = gbhh[2 * RD + c];
    }
    if (w < 4) { mbE = enc_mb[w * 16 + n]; sbE = enc_sb[w * 16 + n]; }
  } else if (w < 12) {
    const int p = w - 8;
    #pragma unroll
    for (int k = 0; k < 4; ++k) {
      const int c = p * 64 + k * 16 + n;
      b1p[k] = pri_b1[c]; b2p[k] = pri_b2[c];
    }
    #pragma unroll
    for (int k = 0; k < 2; ++k) {
      const int r = p * 32 + k * 16 + n;
      bhP[k] = (r < 64) ? pri_mb[r] : pri_sb[r - 64];
    }
  } else {
    const int d_ = w - 12;
    #pragma unroll
    for (int k = 0; k < 4; ++k) {
      const int c = d_ * 64 + k * 16 + n;
      b1d[k] = dec_b1[c]; b2d[k] = dec_b2[c];
    }
    const int r = d_ * 16 + n;
    bhD = (r < 32) ? dec_mb[r] : dec_sb[r - 32];
  }

  // ---- prologue: zero h_0, stage y_0 -> yb[0], y_1 -> yb[1] ----
  for (int i = tid; i < MROWS * (HD / 2); i += NTHR) {
    int row = i >> 7, c = (i & 127) * 2;
    *reinterpret_cast<u32*>(&hbuf[0][row * HS + c]) = 0u;
  }
  if (tid < 256) {
    const int row = tid >> 4, c2 = (tid & 15) * 2;
    f32x2 a0 = nt_ld2(states + ((size_t)0 * BB + r0 + row) * YD + c2);
    f32x2 a1 = nt_ld2(states + ((size_t)1 * BB + r0 + row) * YD + c2);
    yb[0][row * YS + c2] = f2bf(a0[0]); yb[0][row * YS + c2 + 1] = f2bf(a0[1]);
    yb[1][row * YS + c2] = f2bf(a1[0]); yb[1][row * YS + c2 + 1] = f2bf(a1[1]);
  }
  __syncthreads();

  float hreg[2][4];  // A-wave fp32 master h (cols n0A+s*16+n, rows quad*4+i)
  #pragma unroll
  for (int s = 0; s < 2; ++s)
    #pragma unroll
    for (int i = 0; i < 4; ++i) hreg[s][i] = 0.f;

  float kl_acc = 0.f, nll_acc = 0.f;
  int ym0 = 0, ym1 = 1, ym2 = 2;  // yb indices: t%3, (t+1)%3, (t+2)%3 (== (t-1)%3)

  for (int t = 0; t <= TSTEPS; ++t) {
    const int pa = t & 1, pb = pa ^ 1;   // hbuf[pa]=h_t ; hbuf[pb]=h_{t-1}, becomes h_{t+1}
    f32x4 agh[3][2][1] = {};             // A: gh accumulators (r,u,n), persist S1->S4

    // ================ S1 ================
    if (w < 8) {
      if (t < TSTEPS) {
        f32x4 acc[2][1] = {};
        gemm_seg<2,1,1,YS>(acc, wE1, 320, n0A, 0,   yb[ym1], 0, 0, lane);  // x = y_{t+1}
        gemm_seg<2,1,1,YS>(acc, wE1, 320, n0A, 32,  yb[ym0], 0, 0, lane);  // y_t
        gemm_seg<2,1,4,HS>(acc, wE1, 320, n0A, 64,  hbuf[pa], 0,   0, lane);
        gemm_seg<2,1,4,HS>(acc, wE1, 320, n0A, 192, hbuf[pa], 128, 0, lane);
        store_relu_n<2, HBS>(acc, hb1A, n0A, b1e, lane);
        gemm_seg<2,1,4,HS>(agh[0], wGH, 256, n0A, 0,   hbuf[pa], 0,   0, lane); // gh_r
        gemm_seg<2,1,4,HS>(agh[0], wGH, 256, n0A, 128, hbuf[pa], 128, 0, lane);
      }
    } else if (w < 12) {
      if (t > 0) {
        const int n0 = (w - 8) * 64;
        f32x4 acc[4][1] = {};
        gemm_seg<4,1,1,YS>(acc, wP1, 288, n0, 0,   yb[ym2], 0, 0, lane);   // y_{t-1}
        gemm_seg<4,1,4,HS>(acc, wP1, 288, n0, 32,  hbuf[pb], 0,   0, lane);
        gemm_seg<4,1,4,HS>(acc, wP1, 288, n0, 160, hbuf[pb], 128, 0, lane);
        store_relu_n<4, HBS>(acc, hb1P, n0, b1p, lane);
      }
    } else {
      if (t > 0) {
        const int n0 = (w - 12) * 64;
        f32x4 acc[4][1] = {};
        gemm_seg<4,1,1,YS>(acc, wD1, 352, n0, 0,   yb[ym2], 0, 0, lane);   // y_{t-1}
        gemm_seg<4,1,2,ZS>(acc, wD1, 352, n0, 32,  zb[pb], 0, 0, lane);    // z_{t-1}
        gemm_seg<4,1,4,HS>(acc, wD1, 352, n0, 96,  hbuf[pb], 0,   0, lane);
        gemm_seg<4,1,4,HS>(acc, wD1, 352, n0, 224, hbuf[pb], 128, 0, lane);
        store_relu_n<4, HBS>(acc, hb1D, n0, b1d, lane);
      }
    }
    __syncthreads();

    // ================ S2 ================
    if (w < 8) {
      if (t < TSTEPS) {
        f32x4 acc[2][1] = {};
        gemm_seg<2,1,4,HBS>(acc, wE2, 256, n0A, 0,   hb1A, 0,   0, lane);
        gemm_seg<2,1,4,HBS>(acc, wE2, 256, n0A, 128, hb1A, 128, 0, lane);
        store_relu_n<2, HBS>(acc, hb2A, n0A, b2e, lane);
        #pragma unroll
        for (int g = 1; g < 3; ++g) {   // gh_u, gh_n
          gemm_seg<2,1,4,HS>(agh[g], wGH, 256, g * RD + n0A, 0,   hbuf[pa], 0,   0, lane);
          gemm_seg<2,1,4,HS>(agh[g], wGH, 256, g * RD + n0A, 128, hbuf[pa], 128, 0, lane);
        }
      }
    } else if (w < 12) {
      if (t > 0) {
        const int n0 = (w - 8) * 64;
        f32x4 acc[4][1] = {};
        gemm_seg<4,1,4,HBS>(acc, wP2, 256, n0, 0,   hb1P, 0,   0, lane);
        gemm_seg<4,1,4,HBS>(acc, wP2, 256, n0, 128, hb1P, 128, 0, lane);
        store_relu_n<4, HBS>(acc, hb2P, n0, b2p, lane);
      }
    } else {
      if (t > 0) {
        const int n0 = (w - 12) * 64;
        f32x4 acc[4][1] = {};
        gemm_seg<4,1,4,HBS>(acc, wD2, 256, n0, 0,   hb1D, 0,   0, lane);
        gemm_seg<4,1,4,HBS>(acc, wD2, 256, n0, 128, hb1D, 128, 0, lane);
        store_relu_n<4, HBS>(acc, hb2D, n0, b2d, lane);
      }
    }
    __syncthreads();

    // ================ S3 ================
    if (w < 4) {
      if (t < TSTEPS) {
        const int c = w * 16 + n;
        float ev[4];
        #pragma unroll
        for (int i = 0; i < 4; ++i)
          ev[i] = nt_ld(eps + ((size_t)t * BB + r0 + quad * 4 + i) * ZD + c);
        f32x4 am[1][1] = {}, asx[1][1] = {};
        gemm_seg<1,1,8,HBS>(am,  wEH, 256, w * 16,      0, hb2A, 0, 0, lane);
        gemm_seg<1,1,8,HBS>(asx, wEH, 256, 64 + w * 16, 0, hb2A, 0, 0, lane);
        u16* he = hbhE[pa];
        #pragma unroll
        for (int i = 0; i < 4; ++i) {
          const int row = quad * 4 + i;
          u16 bm = f2bf(am[0][0][i] + mbE);
          u16 bs = f2bf(softplus_f(asx[0][0][i] + sbE));
          he[row * HES + c] = bm;
          he[row * HES + 64 + c] = bs;
          zb[pa][row * ZS + c] = f2bf(bf2f(bm) + bf2f(bs) * ev[i]);   // z = em + es*eps
        }
      }
    } else if (w >= 8 && w < 12) {
      if (t > 0) {
        const int p = w - 8, n0 = p * 32;
        f32x4 acc[2][1] = {};
        gemm_seg<2,1,4,HBS>(acc, wPH, 256, n0, 0,   hb2P, 0,   0, lane);
        gemm_seg<2,1,4,HBS>(acc, wPH, 256, n0, 128, hb2P, 128, 0, lane);
        #pragma unroll
        for (int k = 0; k < 2; ++k)
          #pragma unroll
          for (int i = 0; i < 4; ++i) {
            float v = acc[k][0][i] + bhP[k];
            if (p >= 2) v = softplus_f(v);
            hbhP[(quad * 4 + i) * HES + n0 + k * 16 + n] = f2bf(v);
          }
      }
    } else if (w >= 12) {
      if (t > 0) {
        const int d_ = w - 12;
        f32x4 acc[1][1] = {};
        gemm_seg<1,1,4,HBS>(acc, wDH, 256, d_ * 16, 0,   hb2D, 0,   0, lane);
        gemm_seg<1,1,4,HBS>(acc, wDH, 256, d_ * 16, 128, hb2D, 128, 0, lane);
        #pragma unroll
        for (int i = 0; i < 4; ++i) {
          float v = acc[0][0][i] + bhD;
          if (d_ >= 2) v = softplus_f(v);
          hbhD[(quad * 4 + i) * HDS + d_ * 16 + n] = f2bf(v);
        }
      }
    }
    __syncthreads();

    // ================ S4 ================
    if (w < 8) {
      if (t < TSTEPS) {
        f32x4 agi[3][2][1] = {};
        #pragma unroll
        for (int g = 0; g < 3; ++g) {
          gemm_seg<2,1,1,YS>(agi[g], wGI, 96, g * RD + n0A, 0,  yb[ym1], 0, 0, lane); // x
          gemm_seg<2,1,2,ZS>(agi[g], wGI, 96, g * RD + n0A, 32, zb[pa],  0, 0, lane); // z
        }
        u16* hn = hbuf[pb];
        #pragma unroll
        for (int s = 0; s < 2; ++s)
          #pragma unroll
          for (int i = 0; i < 4; ++i) {
            float r = sigmoid_f(agi[0][s][0][i] + agh[0][s][0][i] + brg[s]);
            float u = sigmoid_f(agi[1][s][0][i] + agh[1][s][0][i] + bug[s]);
            float nn = tanh_f(agi[2][s][0][i] + bing[s] + r * (agh[2][s][0][i] + bhng[s]));
            float hv = (1.f - u) * nn + u * hreg[s][i];
            hreg[s][i] = hv;
            hn[(quad * 4 + i) * HS + n0A + s * 16 + n] = f2bf(hv);
          }
      }
    } else if (w < 12) {
      const int e = tid - 512;           // 0..255
      if (t + 2 <= TSTEPS) {             // stage y_{t+2} -> yb[(t+2)%3] (issue load early)
        const int row = e >> 4, c2 = (e & 15) * 2;
        f32x2 v = nt_ld2(states + ((size_t)(t + 2) * BB + r0 + row) * YD + c2);
        u16* dd = &yb[ym2][row * YS + c2];
        dd[0] = f2bf(v[0]); dd[1] = f2bf(v[1]);
      }
      if (t > 0) {                       // KL for step t-1
        const u16* he = hbhE[pb];
        const int m = e >> 4, j0 = e & 15;
        #pragma unroll
        for (int k = 0; k < 4; ++k) {
          const int j = j0 + k * 16;
          float em = bf2f(he[m * HES + j]);
          float es = bf2f(he[m * HES + 64 + j]);
          float pm = bf2f(hbhP[m * HES + j]);
          float ps = bf2f(hbhP[m * HES + 64 + j]);
          float d = em - pm;
          kl_acc += 0.5f * (2.f * __logf(ps * __builtin_amdgcn_rcpf(es))
                            + (es * es + d * d) / (ps * ps) - 1.f);
        }
      }
    } else {
      if (t > 0) {                       // NLL for step t-1 (x_{t-1} = states[t], f32 from global)
        const int e = tid - 768, m = e >> 4, j2 = (e & 15) * 2;
        f32x2 xv = nt_ld2(states + ((size_t)t * BB + r0 + m) * YD + j2);
        #pragma unroll
        for (int c = 0; c < 2; ++c) {
          float dm = bf2f(hbhD[m * HDS + j2 + c]);
          float ds = bf2f(hbhD[m * HDS + 32 + j2 + c]);
          float xf = xv[c];
          float dd = xf - dm;
          nll_acc += __logf(ds) + dd * dd / (2.f * ds * ds) + 0.91893853320467274178f;
        }
      }
    }
    __syncthreads();

    // rotate y triple-buffer indices
    const int tmp = ym0; ym0 = ym1; ym1 = ym2; ym2 = tmp;
  }

  // ---- final reduction: wave shuffle + one atomic per wave ----
  float kv = kl_acc, nv = nll_acc;
  #pragma unroll
  for (int off = 32; off > 0; off >>= 1) {
    kv += __shfl_down(kv, off, 64);
    nv += __shfl_down(nv, off, 64);
  }
  if (lane == 0) {
    atomicAdd(out + 0, kv);
    atomicAdd(out + 1, nv);
  }
}

extern "C" void kernel_launch(void* const* d_in, const int* in_sizes, int n_in,
                              void* d_out, int out_size, void* d_ws, size_t ws_size,
                              hipStream_t stream) {
  const float* states = (const float*)d_in[0];
  const float* eps    = (const float*)d_in[1];
  u16* ws   = (u16*)d_ws;
  float* out = (float*)d_out;

  PrepArgs pa;
  const int jsrc[14] = {2, 4, 6, 8, 10, 12, 14, 16, 18, 20, 22, 24, 26, 27};
  const int joff[14] = {OFF_ENC_W1, OFF_ENC_W2, OFF_ENC_H, OFF_ENC_H + 16384,
                        OFF_PRI_W1, OFF_PRI_W2, OFF_PRI_H, OFF_PRI_H + 16384,
                        OFF_DEC_W1, OFF_DEC_W2, OFF_DEC_H, OFF_DEC_H + 8192,
                        OFF_GWIH, OFF_GWHH};
  const int jcnt[14] = {81920, 65536, 16384, 16384,
                        73728, 65536, 16384, 16384,
                        90112, 65536, 8192, 8192,
                        73728, 196608};
  for (int j = 0; j < 14; ++j) {
    pa.src[j] = (const float*)d_in[jsrc[j]];
    pa.off[j] = joff[j];
    pa.cnt[j] = jcnt[j];
  }

  zero_out_k<<<dim3(1), dim3(64), 0, stream>>>(out);
  prep_weights<<<dim3(64, 14), dim3(256), 0, stream>>>(pa, ws);
  vrnn_kernel<<<dim3(NBLK), dim3(NTHR), 0, stream>>>(
      states, eps,
      (const float*)d_in[3],  (const float*)d_in[5],
      (const float*)d_in[7],  (const float*)d_in[9],
      (const float*)d_in[11], (const float*)d_in[13],
      (const float*)d_in[15], (const float*)d_in[17],
      (const float*)d_in[19], (const float*)d_in[21],
      (const float*)d_in[23], (const float*)d_in[25],
      (const float*)d_in[28], (const float*)d_in[29],
      ws, out);
}

// Round 7
// 9592.374 us; speedup vs baseline: 1.5421x; 1.0457x over previous
//
#include <hip/hip_runtime.h>

typedef unsigned short u16;
typedef unsigned int u32;
typedef __bf16 bf16x8 __attribute__((ext_vector_type(8)));
typedef float f32x4 __attribute__((ext_vector_type(4)));
typedef float f32x2 __attribute__((ext_vector_type(2)));

#define YD 32
#define ZD 64
#define HD 256
#define RD 256
#define TSTEPS 199   // T-1 scan steps
#define BB 2048
#define MROWS 16     // batch rows per block
#define NBLK 128     // 2048/16
#define NTHR 1024    // 16 waves: 0-7=A(recurrence), 8-11=Bp(prior/KL), 12-15=Bd(dec/NLL)
// LDS strides (u16 elements); all *2B are multiples of 16B, pads break pow2 banks
#define YS  40       // y rows (32 + 8 pad)
#define ZS  72       // z rows (64 + 8)
#define HS  264      // h rows (256 + 8)
#define HBS 264      // hidden-layer bufs
#define HES 136      // enc/pri head bufs [m|s](128) + 8
#define HDS 72       // dec head buf [dm|ds](64) + 8

// bf16 weight layout offsets inside d_ws (element units).
// Weights are PRE-SHUFFLED into MFMA fragment order by prep_weights:
//   matrix (N,K) -> fragments [N/16 strips][K/32 segs][64 lanes][8 elems]
//   lane l of fragment (s,g) holds W[s*16 + (l&15)][g*32 + (l>>4)*8 .. +8]
// so each wave's fragment load is ONE fully-coalesced 1KB read.
enum : int {
  OFF_ENC_W1 = 0,        // 256x320
  OFF_ENC_W2 = 81920,    // 256x256
  OFF_ENC_H  = 147456,   // [enc_mw;enc_sw] 128x256
  OFF_PRI_W1 = 180224,   // 256x288
  OFF_PRI_W2 = 253952,   // 256x256
  OFF_PRI_H  = 319488,   // [pri_mw;pri_sw] 128x256
  OFF_DEC_W1 = 352256,   // 256x352
  OFF_DEC_W2 = 442368,   // 256x256
  OFF_DEC_H  = 507904,   // [dec_mw;dec_sw] 64x256
  OFF_GWIH   = 524288,   // 768x96
  OFF_GWHH   = 598016,   // 768x256
};

__device__ __forceinline__ u16 f2bf(float f) {
  u32 u = __float_as_uint(f);
  u += 0x7fffu + ((u >> 16) & 1u);   // RTNE
  return (u16)(u >> 16);
}
__device__ __forceinline__ float bf2f(u16 b) {
  return __uint_as_float((u32)b << 16);
}
__device__ __forceinline__ float softplus_f(float x) {
  float l = __logf(1.f + __expf(-fabsf(x)));
  return x > 0.f ? x + l : l;
}
__device__ __forceinline__ float sigmoid_f(float x) {
  return __builtin_amdgcn_rcpf(1.f + __expf(-x));
}
__device__ __forceinline__ float tanh_f(float x) {
  float e = __expf(-2.f * fabsf(x));
  float t = (1.f - e) * __builtin_amdgcn_rcpf(1.f + e);
  return x >= 0.f ? t : -t;
}
__device__ __forceinline__ f32x2 nt_ld2(const float* p) {
  return __builtin_nontemporal_load(reinterpret_cast<const f32x2*>(p));
}
__device__ __forceinline__ float nt_ld(const float* p) {
  return __builtin_nontemporal_load(p);
}

// Wave-level GEMM over one contiguous K-segment.
// B from pre-shuffled fragments: base + ((strip)*(Kw/32)+seg)*512 + lane*8 —
// one coalesced 1KB global load per fragment.
// A (LDS, row-major, stride AS): rows (rt0+rt)*16+(lane&15), cols acol0+ks*32+quad*8
// D[nt][rt] += sum_k A[m][k]*W[n][k]  (act @ W.T)
template<int NT, int RT, int KS, int AS>
__device__ __forceinline__ void gemm_seg(f32x4 (&acc)[NT][RT],
    const u16* __restrict__ W, const int Kw, const int wrow0, const int wk0,
    const u16* A, const int acol0, const int rt0, const int lane)
{
  const int n = lane & 15, quad = lane >> 4;
  const int nseg = Kw >> 5;
  bf16x8 b[KS][NT];
  #pragma unroll
  for (int nt = 0; nt < NT; ++nt) {
    const u16* wp = W + (size_t)((((wrow0 >> 4) + nt) * nseg) + (wk0 >> 5)) * 512 + lane * 8;
    #pragma unroll
    for (int ks = 0; ks < KS; ++ks)
      b[ks][nt] = *reinterpret_cast<const bf16x8*>(wp + ks * 512);
  }
  #pragma unroll
  for (int ks = 0; ks < KS; ++ks) {
    bf16x8 a[RT];
    #pragma unroll
    for (int rt = 0; rt < RT; ++rt)
      a[rt] = *reinterpret_cast<const bf16x8*>(A + ((rt0 + rt) * 16 + n) * AS + acol0 + ks * 32 + quad * 8);
    #pragma unroll
    for (int nt = 0; nt < NT; ++nt)
      #pragma unroll
      for (int rt = 0; rt < RT; ++rt)
        acc[nt][rt] = __builtin_amdgcn_mfma_f32_16x16x32_bf16(a[rt], b[ks][nt], acc[nt][rt], 0, 0, 0);
  }
}

// bias + ReLU + bf16 store (RT=1, NT strips of 16 cols)
template<int NT, int DS>
__device__ __forceinline__ void store_relu_n(const f32x4 (&acc)[NT][1], u16* dst,
    const int col0, const float (&bias)[NT], const int lane)
{
  const int n = lane & 15, quad = lane >> 4;
  #pragma unroll
  for (int nt = 0; nt < NT; ++nt)
    #pragma unroll
    for (int i = 0; i < 4; ++i) {
      float v = fmaxf(acc[nt][0][i] + bias[nt], 0.f);
      dst[(quad * 4 + i) * DS + col0 + nt * 16 + n] = f2bf(v);
    }
}

struct PrepArgs { const float* src[14]; int off[14]; int cnt[14]; int kd[14]; };

// Shuffle f32 weights (N,K row-major) into bf16 MFMA-fragment order:
// out[i]: i = ((strip*nseg + seg)*64 + l)*8 + e
//   -> src[(strip*16 + (l&15)) * K + seg*32 + (l>>4)*8 + e]
__global__ void prep_weights(PrepArgs a, u16* __restrict__ dst) {
  const int j = blockIdx.y;
  const float* __restrict__ s = a.src[j];
  u16* d = dst + a.off[j];
  const int nel = a.cnt[j];
  const int K = a.kd[j];
  const int nseg = K >> 5;
  for (int i = blockIdx.x * blockDim.x + threadIdx.x; i < nel; i += gridDim.x * blockDim.x) {
    const int f = i >> 9;              // fragment index (512 elems each)
    const int r = i & 511;
    const int l = r >> 3, e = r & 7;
    const int row = (f / nseg) * 16 + (l & 15);
    const int col = (f % nseg) * 32 + ((l >> 4) << 3) + e;
    d[i] = f2bf(s[row * K + col]);
  }
}

__global__ void zero_out_k(float* out) { if (threadIdx.x < 2) out[threadIdx.x] = 0.f; }

// 4-slot / 3-role pipelined schedule (R6 structure; weights now read via
// coalesced fragment layout):
//   A  (waves 0-7):  step t   : S1 enc1+gh_r | S2 enc2+gh_un | S3 encH+z | S4 gi+gates+h_new
//   Bp (waves 8-11): step t-1 : S1 pri1      | S2 pri2       | S3 priH   | S4 KL + stage y_{t+2}
//   Bd (waves 12-15):step t-1 : S1 dec1      | S2 dec2       | S3 decH   | S4 NLL
// Buffers: h double (parity t&1 holds h_t), z double, hbhE double, y triple (t%3).
__global__ __launch_bounds__(NTHR, 4)
void vrnn_kernel(const float* __restrict__ states, const float* __restrict__ eps,
                 const float* __restrict__ enc_b1, const float* __restrict__ enc_b2,
                 const float* __restrict__ enc_mb, const float* __restrict__ enc_sb,
                 const float* __restrict__ pri_b1, const float* __restrict__ pri_b2,
                 const float* __restrict__ pri_mb, const float* __restrict__ pri_sb,
                 const float* __restrict__ dec_b1, const float* __restrict__ dec_b2,
                 const float* __restrict__ dec_mb, const float* __restrict__ dec_sb,
                 const float* __restrict__ gbih, const float* __restrict__ gbhh,
                 const u16* __restrict__ ws, float* __restrict__ out)
{
  __shared__ __align__(16) u16 yb[3][MROWS * YS];     // y_t triple buffer (t%3)
  __shared__ __align__(16) u16 zb[2][MROWS * ZS];     // z_t double buffer (t&1)
  __shared__ __align__(16) u16 hbuf[2][MROWS * HS];   // h_t double buffer (t&1)
  __shared__ __align__(16) u16 hb1A[MROWS * HBS], hb2A[MROWS * HBS];
  __shared__ __align__(16) u16 hb1P[MROWS * HBS], hb2P[MROWS * HBS];
  __shared__ __align__(16) u16 hb1D[MROWS * HBS], hb2D[MROWS * HBS];
  __shared__ __align__(16) u16 hbhE[2][MROWS * HES];  // enc heads double buffer (t&1)
  __shared__ __align__(16) u16 hbhP[MROWS * HES];
  __shared__ __align__(16) u16 hbhD[MROWS * HDS];

  const int tid = threadIdx.x;
  const int w = tid >> 6, lane = tid & 63;
  const int n = lane & 15, quad = lane >> 4;
  const int r0 = blockIdx.x * MROWS;
  const int n0A = w * 32;   // A-wave 32-col strip base (valid for w<8)

  const u16* __restrict__ wE1 = ws + OFF_ENC_W1;
  const u16* __restrict__ wE2 = ws + OFF_ENC_W2;
  const u16* __restrict__ wEH = ws + OFF_ENC_H;
  const u16* __restrict__ wP1 = ws + OFF_PRI_W1;
  const u16* __restrict__ wP2 = ws + OFF_PRI_W2;
  const u16* __restrict__ wPH = ws + OFF_PRI_H;
  const u16* __restrict__ wD1 = ws + OFF_DEC_W1;
  const u16* __restrict__ wD2 = ws + OFF_DEC_W2;
  const u16* __restrict__ wDH = ws + OFF_DEC_H;
  const u16* __restrict__ wGI = ws + OFF_GWIH;
  const u16* __restrict__ wGH = ws + OFF_GWHH;

  // ---- role-specific hoisted bias scalars ----
  float b1e[2] = {}, b2e[2] = {}, brg[2] = {}, bug[2] = {}, bing[2] = {}, bhng[2] = {};
  float mbE = 0.f, sbE = 0.f;
  float b1p[4] = {}, b2p[4] = {}, bhP[2] = {};
  float b1d[4] = {}, b2d[4] = {}, bhD = 0.f;
  if (w < 8) {
    #pragma unroll
    for (int s = 0; s < 2; ++s) {
      const int c = n0A + s * 16 + n;
      b1e[s] = enc_b1[c]; b2e[s] = enc_b2[c];
      brg[s] = gbih[c] + gbhh[c];
      bug[s] = gbih[RD + c] + gbhh[RD + c];
      bing[s] = gbih[2 * RD + c];
      bhng[s] = gbhh[2 * RD + c];
    }
    if (w < 4) { mbE = enc_mb[w * 16 + n]; sbE = enc_sb[w * 16 + n]; }
  } else if (w < 12) {
    const int p = w - 8;
    #pragma unroll
    for (int k = 0; k < 4; ++k) {
      const int c = p * 64 + k * 16 + n;
      b1p[k] = pri_b1[c]; b2p[k] = pri_b2[c];
    }
    #pragma unroll
    for (int k = 0; k < 2; ++k) {
      const int r = p * 32 + k * 16 + n;
      bhP[k] = (r < 64) ? pri_mb[r] : pri_sb[r - 64];
    }
  } else {
    const int d_ = w - 12;
    #pragma unroll
    for (int k = 0; k < 4; ++k) {
      const int c = d_ * 64 + k * 16 + n;
      b1d[k] = dec_b1[c]; b2d[k] = dec_b2[c];
    }
    const int r = d_ * 16 + n;
    bhD = (r < 32) ? dec_mb[r] : dec_sb[r - 32];
  }

  // ---- prologue: zero h_0, stage y_0 -> yb[0], y_1 -> yb[1] ----
  for (int i = tid; i < MROWS * (HD / 2); i += NTHR) {
    int row = i >> 7, c = (i & 127) * 2;
    *reinterpret_cast<u32*>(&hbuf[0][row * HS + c]) = 0u;
  }
  if (tid < 256) {
    const int row = tid >> 4, c2 = (tid & 15) * 2;
    f32x2 a0 = nt_ld2(states + ((size_t)0 * BB + r0 + row) * YD + c2);
    f32x2 a1 = nt_ld2(states + ((size_t)1 * BB + r0 + row) * YD + c2);
    yb[0][row * YS + c2] = f2bf(a0[0]); yb[0][row * YS + c2 + 1] = f2bf(a0[1]);
    yb[1][row * YS + c2] = f2bf(a1[0]); yb[1][row * YS + c2 + 1] = f2bf(a1[1]);
  }
  __syncthreads();

  float hreg[2][4];  // A-wave fp32 master h (cols n0A+s*16+n, rows quad*4+i)
  #pragma unroll
  for (int s = 0; s < 2; ++s)
    #pragma unroll
    for (int i = 0; i < 4; ++i) hreg[s][i] = 0.f;

  float kl_acc = 0.f, nll_acc = 0.f;
  int ym0 = 0, ym1 = 1, ym2 = 2;  // yb indices: t%3, (t+1)%3, (t+2)%3 (== (t-1)%3)

  for (int t = 0; t <= TSTEPS; ++t) {
    const int pa = t & 1, pb = pa ^ 1;   // hbuf[pa]=h_t ; hbuf[pb]=h_{t-1}, becomes h_{t+1}
    f32x4 agh[3][2][1] = {};             // A: gh accumulators (r,u,n), persist S1->S4

    // ================ S1 ================
    if (w < 8) {
      if (t < TSTEPS) {
        f32x4 acc[2][1] = {};
        gemm_seg<2,1,1,YS>(acc, wE1, 320, n0A, 0,   yb[ym1], 0, 0, lane);  // x = y_{t+1}
        gemm_seg<2,1,1,YS>(acc, wE1, 320, n0A, 32,  yb[ym0], 0, 0, lane);  // y_t
        gemm_seg<2,1,4,HS>(acc, wE1, 320, n0A, 64,  hbuf[pa], 0,   0, lane);
        gemm_seg<2,1,4,HS>(acc, wE1, 320, n0A, 192, hbuf[pa], 128, 0, lane);
        store_relu_n<2, HBS>(acc, hb1A, n0A, b1e, lane);
        gemm_seg<2,1,4,HS>(agh[0], wGH, 256, n0A, 0,   hbuf[pa], 0,   0, lane); // gh_r
        gemm_seg<2,1,4,HS>(agh[0], wGH, 256, n0A, 128, hbuf[pa], 128, 0, lane);
      }
    } else if (w < 12) {
      if (t > 0) {
        const int n0 = (w - 8) * 64;
        f32x4 acc[4][1] = {};
        gemm_seg<4,1,1,YS>(acc, wP1, 288, n0, 0,   yb[ym2], 0, 0, lane);   // y_{t-1}
        gemm_seg<4,1,4,HS>(acc, wP1, 288, n0, 32,  hbuf[pb], 0,   0, lane);
        gemm_seg<4,1,4,HS>(acc, wP1, 288, n0, 160, hbuf[pb], 128, 0, lane);
        store_relu_n<4, HBS>(acc, hb1P, n0, b1p, lane);
      }
    } else {
      if (t > 0) {
        const int n0 = (w - 12) * 64;
        f32x4 acc[4][1] = {};
        gemm_seg<4,1,1,YS>(acc, wD1, 352, n0, 0,   yb[ym2], 0, 0, lane);   // y_{t-1}
        gemm_seg<4,1,2,ZS>(acc, wD1, 352, n0, 32,  zb[pb], 0, 0, lane);    // z_{t-1}
        gemm_seg<4,1,4,HS>(acc, wD1, 352, n0, 96,  hbuf[pb], 0,   0, lane);
        gemm_seg<4,1,4,HS>(acc, wD1, 352, n0, 224, hbuf[pb], 128, 0, lane);
        store_relu_n<4, HBS>(acc, hb1D, n0, b1d, lane);
      }
    }
    __syncthreads();

    // ================ S2 ================
    if (w < 8) {
      if (t < TSTEPS) {
        f32x4 acc[2][1] = {};
        gemm_seg<2,1,4,HBS>(acc, wE2, 256, n0A, 0,   hb1A, 0,   0, lane);
        gemm_seg<2,1,4,HBS>(acc, wE2, 256, n0A, 128, hb1A, 128, 0, lane);
        store_relu_n<2, HBS>(acc, hb2A, n0A, b2e, lane);
        #pragma unroll
        for (int g = 1; g < 3; ++g) {   // gh_u, gh_n
          gemm_seg<2,1,4,HS>(agh[g], wGH, 256, g * RD + n0A, 0,   hbuf[pa], 0,   0, lane);
          gemm_seg<2,1,4,HS>(agh[g], wGH, 256, g * RD + n0A, 128, hbuf[pa], 128, 0, lane);
        }
      }
    } else if (w < 12) {
      if (t > 0) {
        const int n0 = (w - 8) * 64;
        f32x4 acc[4][1] = {};
        gemm_seg<4,1,4,HBS>(acc, wP2, 256, n0, 0,   hb1P, 0,   0, lane);
        gemm_seg<4,1,4,HBS>(acc, wP2, 256, n0, 128, hb1P, 128, 0, lane);
        store_relu_n<4, HBS>(acc, hb2P, n0, b2p, lane);
      }
    } else {
      if (t > 0) {
        const int n0 = (w - 12) * 64;
        f32x4 acc[4][1] = {};
        gemm_seg<4,1,4,HBS>(acc, wD2, 256, n0, 0,   hb1D, 0,   0, lane);
        gemm_seg<4,1,4,HBS>(acc, wD2, 256, n0, 128, hb1D, 128, 0, lane);
        store_relu_n<4, HBS>(acc, hb2D, n0, b2d, lane);
      }
    }
    __syncthreads();

    // ================ S3 ================
    if (w < 4) {
      if (t < TSTEPS) {
        const int c = w * 16 + n;
        float ev[4];
        #pragma unroll
        for (int i = 0; i < 4; ++i)
          ev[i] = nt_ld(eps + ((size_t)t * BB + r0 + quad * 4 + i) * ZD + c);
        f32x4 am[1][1] = {}, asx[1][1] = {};
        gemm_seg<1,1,8,HBS>(am,  wEH, 256, w * 16,      0, hb2A, 0, 0, lane);
        gemm_seg<1,1,8,HBS>(asx, wEH, 256, 64 + w * 16, 0, hb2A, 0, 0, lane);
        u16* he = hbhE[pa];
        #pragma unroll
        for (int i = 0; i < 4; ++i) {
          const int row = quad * 4 + i;
          u16 bm = f2bf(am[0][0][i] + mbE);
          u16 bs = f2bf(softplus_f(asx[0][0][i] + sbE));
          he[row * HES + c] = bm;
          he[row * HES + 64 + c] = bs;
          zb[pa][row * ZS + c] = f2bf(bf2f(bm) + bf2f(bs) * ev[i]);   // z = em + es*eps
        }
      }
    } else if (w >= 8 && w < 12) {
      if (t > 0) {
        const int p = w - 8, n0 = p * 32;
        f32x4 acc[2][1] = {};
        gemm_seg<2,1,4,HBS>(acc, wPH, 256, n0, 0,   hb2P, 0,   0, lane);
        gemm_seg<2,1,4,HBS>(acc, wPH, 256, n0, 128, hb2P, 128, 0, lane);
        #pragma unroll
        for (int k = 0; k < 2; ++k)
          #pragma unroll
          for (int i = 0; i < 4; ++i) {
            float v = acc[k][0][i] + bhP[k];
            if (p >= 2) v = softplus_f(v);
            hbhP[(quad * 4 + i) * HES + n0 + k * 16 + n] = f2bf(v);
          }
      }
    } else if (w >= 12) {
      if (t > 0) {
        const int d_ = w - 12;
        f32x4 acc[1][1] = {};
        gemm_seg<1,1,4,HBS>(acc, wDH, 256, d_ * 16, 0,   hb2D, 0,   0, lane);
        gemm_seg<1,1,4,HBS>(acc, wDH, 256, d_ * 16, 128, hb2D, 128, 0, lane);
        #pragma unroll
        for (int i = 0; i < 4; ++i) {
          float v = acc[0][0][i] + bhD;
          if (d_ >= 2) v = softplus_f(v);
          hbhD[(quad * 4 + i) * HDS + d_ * 16 + n] = f2bf(v);
        }
      }
    }
    __syncthreads();

    // ================ S4 ================
    if (w < 8) {
      if (t < TSTEPS) {
        f32x4 agi[3][2][1] = {};
        #pragma unroll
        for (int g = 0; g < 3; ++g) {
          gemm_seg<2,1,1,YS>(agi[g], wGI, 96, g * RD + n0A, 0,  yb[ym1], 0, 0, lane); // x
          gemm_seg<2,1,2,ZS>(agi[g], wGI, 96, g * RD + n0A, 32, zb[pa],  0, 0, lane); // z
        }
        u16* hn = hbuf[pb];
        #pragma unroll
        for (int s = 0; s < 2; ++s)
          #pragma unroll
          for (int i = 0; i < 4; ++i) {
            float r = sigmoid_f(agi[0][s][0][i] + agh[0][s][0][i] + brg[s]);
            float u = sigmoid_f(agi[1][s][0][i] + agh[1][s][0][i] + bug[s]);
            float nn = tanh_f(agi[2][s][0][i] + bing[s] + r * (agh[2][s][0][i] + bhng[s]));
            float hv = (1.f - u) * nn + u * hreg[s][i];
            hreg[s][i] = hv;
            hn[(quad * 4 + i) * HS + n0A + s * 16 + n] = f2bf(hv);
          }
      }
    } else if (w < 12) {
      const int e = tid - 512;           // 0..255
      if (t + 2 <= TSTEPS) {             // stage y_{t+2} -> yb[(t+2)%3] (issue load early)
        const int row = e >> 4, c2 = (e & 15) * 2;
        f32x2 v = nt_ld2(states + ((size_t)(t + 2) * BB + r0 + row) * YD + c2);
        u16* dd = &yb[ym2][row * YS + c2];
        dd[0] = f2bf(v[0]); dd[1] = f2bf(v[1]);
      }
      if (t > 0) {                       // KL for step t-1
        const u16* he = hbhE[pb];
        const int m = e >> 4, j0 = e & 15;
        #pragma unroll
        for (int k = 0; k < 4; ++k) {
          const int j = j0 + k * 16;
          float em = bf2f(he[m * HES + j]);
          float es = bf2f(he[m * HES + 64 + j]);
          float pm = bf2f(hbhP[m * HES + j]);
          float ps = bf2f(hbhP[m * HES + 64 + j]);
          float d = em - pm;
          kl_acc += 0.5f * (2.f * __logf(ps * __builtin_amdgcn_rcpf(es))
                            + (es * es + d * d) / (ps * ps) - 1.f);
        }
      }
    } else {
      if (t > 0) {                       // NLL for step t-1 (x_{t-1} = states[t], f32 from global)
        const int e = tid - 768, m = e >> 4, j2 = (e & 15) * 2;
        f32x2 xv = nt_ld2(states + ((size_t)t * BB + r0 + m) * YD + j2);
        #pragma unroll
        for (int c = 0; c < 2; ++c) {
          float dm = bf2f(hbhD[m * HDS + j2 + c]);
          float ds = bf2f(hbhD[m * HDS + 32 + j2 + c]);
          float xf = xv[c];
          float dd = xf - dm;
          nll_acc += __logf(ds) + dd * dd / (2.f * ds * ds) + 0.91893853320467274178f;
        }
      }
    }
    __syncthreads();

    // rotate y triple-buffer indices
    const int tmp = ym0; ym0 = ym1; ym1 = ym2; ym2 = tmp;
  }

  // ---- final reduction: wave shuffle + one atomic per wave ----
  float kv = kl_acc, nv = nll_acc;
  #pragma unroll
  for (int off = 32; off > 0; off >>= 1) {
    kv += __shfl_down(kv, off, 64);
    nv += __shfl_down(nv, off, 64);
  }
  if (lane == 0) {
    atomicAdd(out + 0, kv);
    atomicAdd(out + 1, nv);
  }
}

extern "C" void kernel_launch(void* const* d_in, const int* in_sizes, int n_in,
                              void* d_out, int out_size, void* d_ws, size_t ws_size,
                              hipStream_t stream) {
  const float* states = (const float*)d_in[0];
  const float* eps    = (const float*)d_in[1];
  u16* ws   = (u16*)d_ws;
  float* out = (float*)d_out;

  PrepArgs pa;
  const int jsrc[14] = {2, 4, 6, 8, 10, 12, 14, 16, 18, 20, 22, 24, 26, 27};
  const int joff[14] = {OFF_ENC_W1, OFF_ENC_W2, OFF_ENC_H, OFF_ENC_H + 16384,
                        OFF_PRI_W1, OFF_PRI_W2, OFF_PRI_H, OFF_PRI_H + 16384,
                        OFF_DEC_W1, OFF_DEC_W2, OFF_DEC_H, OFF_DEC_H + 8192,
                        OFF_GWIH, OFF_GWHH};
  const int jcnt[14] = {81920, 65536, 16384, 16384,
                        73728, 65536, 16384, 16384,
                        90112, 65536, 8192, 8192,
                        73728, 196608};
  const int jkd[14]  = {320, 256, 256, 256,
                        288, 256, 256, 256,
                        352, 256, 256, 256,
                        96, 256};
  for (int j = 0; j < 14; ++j) {
    pa.src[j] = (const float*)d_in[jsrc[j]];
    pa.off[j] = joff[j];
    pa.cnt[j] = jcnt[j];
    pa.kd[j]  = jkd[j];
  }

  zero_out_k<<<dim3(1), dim3(64), 0, stream>>>(out);
  prep_weights<<<dim3(64, 14), dim3(256), 0, stream>>>(pa, ws);
  vrnn_kernel<<<dim3(NBLK), dim3(NTHR), 0, stream>>>(
      states, eps,
      (const float*)d_in[3],  (const float*)d_in[5],
      (const float*)d_in[7],  (const float*)d_in[9],
      (const float*)d_in[11], (const float*)d_in[13],
      (const float*)d_in[15], (const float*)d_in[17],
      (const float*)d_in[19], (const float*)d_in[21],
      (const float*)d_in[23], (const float*)d_in[25],
      (const float*)d_in[28], (const float*)d_in[29],
      ws, out);
}